// Round 1
// 327.419 us; speedup vs baseline: 1.0502x; 1.0502x over previous
//
#include <hip/hip_runtime.h>
#include <stdint.h>
#include <math.h>

// Problem constants (hard-coded in reference)
#define NBBOX 8192
#define FDIM  4096
#define H1DIM 64
#define H2DIM 32
#define NW    16
#define NCOL  1024   // NW * H1DIM

typedef __attribute__((ext_vector_type(8))) _Float16 f16x8;
typedef __attribute__((ext_vector_type(4))) float    f32x4;

typedef __attribute__((address_space(1))) void* gptr_t;
typedef __attribute__((address_space(3))) void* lptr_t;

// async global->LDS, 16B per lane; LDS dest is wave-uniform base + lane*16
__device__ __forceinline__ void g2l16(const void* g, void* l) {
    __builtin_amdgcn_global_load_lds((gptr_t)(uintptr_t)g,
                                     (lptr_t)(uint32_t)(uintptr_t)l,
                                     16, 0, 0);
}

// ---------------- kernel 1: fused prep ----------------
// bx < 512  : gather+transpose W1[words] -> bth[1024][4096] fp16 (16 words x 32 f-tiles)
// bx >= 512 : x fp32 -> fp16 (16384 blocks, 8 floats/thread)
__global__ __launch_bounds__(256) void prep(
    const float* __restrict__ x, _Float16* __restrict__ xh,
    const float* __restrict__ W1, const int* __restrict__ words,
    uint32_t* __restrict__ bth_u32)
{
    __shared__ uint32_t t[64 * 69];   // [c][f/2], pad 69 -> conflict-free
    const int tid = threadIdx.x;

    if (blockIdx.x >= 512) {
        // ---- convert path ----
        const int gid = (blockIdx.x - 512) * 256 + tid;
        const int idx = gid * 8;
        float4 a = *(const float4*)(x + idx);
        float4 b = *(const float4*)(x + idx + 4);
        f16x8 h;
        h[0] = (_Float16)a.x; h[1] = (_Float16)a.y; h[2] = (_Float16)a.z; h[3] = (_Float16)a.w;
        h[4] = (_Float16)b.x; h[5] = (_Float16)b.y; h[6] = (_Float16)b.z; h[7] = (_Float16)b.w;
        *(f16x8*)(xh + idx) = h;
        return;
    }

    // ---- gather path ----
    const int wi = blockIdx.x >> 5;
    const int ft = blockIdx.x & 31;
    const int f0 = ft * 128;
    const int w  = words[wi];
    const int c    = tid & 63;
    const int fgrp = tid >> 6;       // 0..3

    const float* src = W1 + ((size_t)w * FDIM + f0) * H1DIM + c;
#pragma unroll
    for (int p = 0; p < 16; ++p) {
        const int f = fgrp * 2 + p * 8;          // even f in 0..126
        float v0 = src[(size_t)f * H1DIM];        // coalesced (c contiguous)
        float v1 = src[(size_t)(f + 1) * H1DIM];
        union { _Float16 h[2]; uint32_t u; } pk;
        pk.h[0] = (_Float16)v0; pk.h[1] = (_Float16)v1;
        t[c * 69 + (f >> 1)] = pk.u;
    }
    __syncthreads();
#pragma unroll
    for (int p = 0; p < 16; ++p) {
        const int cc = p * 4 + (tid >> 6);
        const int fd = tid & 63;
        bth_u32[(size_t)(wi * 64 + cc) * (FDIM / 2) + ft * 64 + fd] = t[cc * 69 + fd];
    }
}

// ---------------- kernel 2: fused GEMM + tail MLP ----------------
// 128x128 tile, BK=64 as 2 packed 32-wide panels, 4 waves, 16x16x32 MFMA.
// Block map: mt = bx&63, nt = bx>>6  -> the 8 blocks sharing an A M-tile are
// bx == mt (mod 8) => same XCD under round-robin dispatch => A fetched once/XCD.
// Epilogue: each wave's 64x64 quadrant is one word's full H1 slab for 64 rows;
// run layer2+layer3+sigmoid per-wave from an LDS-staged tile (unioned over As/Bs).
__global__ __launch_bounds__(256, 2) void gemm_fused(
    const _Float16* __restrict__ xh, const _Float16* __restrict__ bth,
    const float* __restrict__ b1, const int* __restrict__ words,
    const float* __restrict__ W2, const float* __restrict__ b2,
    const float* __restrict__ W3, const float* __restrict__ b3,
    float* __restrict__ sig)   // [NW][NBBOX]
{
    __shared__ __align__(16) char smem[65536];
    _Float16 (*As)[128 * 32] = (_Float16 (*)[128 * 32])smem;            // 2 x 8 KB
    _Float16 (*Bs)[128 * 32] = (_Float16 (*)[128 * 32])(smem + 16384);  // 2 x 8 KB
    float* tile = (float*)smem;   // 64 KB, reused AFTER the final k-loop barrier

    const int mt   = blockIdx.x & 63;   // 64 M-tiles
    const int nt   = blockIdx.x >> 6;   // 8 N-tiles
    const int t    = threadIdx.x;
    const int w    = t >> 6;
    const int lane = t & 63;
    const int m0 = mt * 128, n0 = nt * 128;

    f32x4 acc[4][4] = {};

    const int rs = w * 16 + (lane >> 2);
    const int kc = (lane & 3) * 8;

    const _Float16* A = xh  + (size_t)m0 * FDIM;
    const _Float16* B = bth + (size_t)n0 * FDIM;

    const int wm = w >> 1, wn = w & 1;
    const int ml = lane & 15;
    const int q8 = (lane >> 4) * 8;

    for (int kt = 0; kt < 64; ++kt) {
        const int k0 = kt * 64;
#pragma unroll
        for (int s = 0; s < 2; ++s) {
            const int kp = k0 + s * 32 + kc;
            g2l16(A + (size_t)rs * FDIM + kp,        &As[s][w * 512]);
            g2l16(A + (size_t)(rs + 64) * FDIM + kp, &As[s][2048 + w * 512]);
            g2l16(B + (size_t)rs * FDIM + kp,        &Bs[s][w * 512]);
            g2l16(B + (size_t)(rs + 64) * FDIM + kp, &Bs[s][2048 + w * 512]);
        }
        __syncthreads();

#pragma unroll
        for (int s = 0; s < 2; ++s) {
            f16x8 af[4], bfr[4];
#pragma unroll
            for (int i = 0; i < 4; ++i)
                af[i] = *(const f16x8*)&As[s][(wm * 64 + i * 16 + ml) * 32 + q8];
#pragma unroll
            for (int j = 0; j < 4; ++j)
                bfr[j] = *(const f16x8*)&Bs[s][(wn * 64 + j * 16 + ml) * 32 + q8];
#pragma unroll
            for (int i = 0; i < 4; ++i)
#pragma unroll
                for (int j = 0; j < 4; ++j)
                    acc[i][j] = __builtin_amdgcn_mfma_f32_16x16x32_f16(af[i], bfr[j], acc[i][j], 0, 0, 0);
        }
        __syncthreads();   // final iteration: also guards the As/Bs -> tile reuse
    }

    // ---- epilogue: bias+relu into wave-private swizzled LDS tile ----
    // C/D layout: col=lane&15, row=quad*4+reg  [m89-verified]
    const int q  = lane >> 4;
    const int wi = nt * 2 + wn;                                   // word slot 0..15
    const int wv = __builtin_amdgcn_readfirstlane(words[wi]);     // force SGPR
    float* tw = tile + w * 4096;                                  // [64 rows][64 k]

#pragma unroll
    for (int j = 0; j < 4; ++j) {
        const int col = j * 16 + ml;                              // k within word, 0..63
        const float bias = b1[wv * H1DIM + col];
        const int c = col >> 2, e = col & 3;
#pragma unroll
        for (int i = 0; i < 4; ++i) {
#pragma unroll
            for (int r = 0; r < 4; ++r) {
                const int row = i * 16 + q * 4 + r;               // local row 0..63
                const int pos = ((c + row) & 7) | (c & 8);        // chunk swizzle
                float v = acc[i][j][r] + bias;
                tw[row * 64 + pos * 4 + e] = v > 0.f ? v : 0.f;
            }
        }
    }
    // wave-private LDS: no barrier needed (compiler inserts lgkmcnt waits)

    // ---- layer 2+3 + sigmoid, one row per lane ----
    const float* W2w = W2 + (size_t)wv * (H1DIM * H2DIM);
    float a2[H2DIM];
#pragma unroll
    for (int j = 0; j < H2DIM; ++j) a2[j] = 0.f;

#pragma unroll
    for (int c2 = 0; c2 < 16; ++c2) {
        const int pos = ((c2 + lane) & 7) | (c2 & 8);
        f32x4 h = *(const f32x4*)&tw[lane * 64 + pos * 4];
#pragma unroll
        for (int kk = 0; kk < 4; ++kk) {
            const float hv = h[kk];
            const int k = c2 * 4 + kk;
#pragma unroll
            for (int j = 0; j < H2DIM; ++j)
                a2[j] = fmaf(hv, W2w[k * H2DIM + j], a2[j]);
        }
    }

    float logit = b3[wv];
#pragma unroll
    for (int j = 0; j < H2DIM; ++j) {
        float h2 = a2[j] + b2[wv * H2DIM + j];
        h2 = h2 > 0.f ? h2 : 0.f;
        logit = fmaf(h2, W3[wv * H2DIM + j], logit);
    }
    sig[(size_t)wi * NBBOX + m0 + wm * 64 + lane] = 1.f / (1.f + expf(-logit));
}

// ---------------- kernel 3: product over words ----------------
__global__ void prod_k(const float* __restrict__ sig, float* __restrict__ out) {
    const int r = blockIdx.x * 256 + threadIdx.x;
    float p = 1.f;
#pragma unroll
    for (int wi = 0; wi < NW; ++wi) p *= sig[(size_t)wi * NBBOX + r];
    out[r] = p;
}

extern "C" void kernel_launch(void* const* d_in, const int* in_sizes, int n_in,
                              void* d_out, int out_size, void* d_ws, size_t ws_size,
                              hipStream_t stream)
{
    const float* x   = (const float*)d_in[1];
    const int* words = (const int*)  d_in[2];
    const float* W1  = (const float*)d_in[3];
    const float* b1  = (const float*)d_in[4];
    const float* W2  = (const float*)d_in[5];
    const float* b2  = (const float*)d_in[6];
    const float* W3  = (const float*)d_in[7];
    const float* b3  = (const float*)d_in[8];
    float* out = (float*)d_out;

    char* ws = (char*)d_ws;
    _Float16* xh  = (_Float16*)(ws);                         // 8192*4096*2  = 64 MiB
    _Float16* bth = (_Float16*)(ws + 67108864);              // 1024*4096*2  = 8 MiB
    float*    sig = (float*)   (ws + 67108864 + 8388608);    // 16*8192*4    = 512 KiB

    prep<<<512 + NBBOX * FDIM / 8 / 256, 256, 0, stream>>>(x, xh, W1, words, (uint32_t*)bth);
    gemm_fused<<<512, 256, 0, stream>>>(xh, bth, b1, words, W2, b2, W3, b3, sig);
    prod_k<<<NBBOX / 256, 256, 0, stream>>>(sig, out);
}

// Round 2
// 317.495 us; speedup vs baseline: 1.0830x; 1.0313x over previous
//
#include <hip/hip_runtime.h>
#include <stdint.h>
#include <math.h>

// Problem constants (hard-coded in reference)
#define NBBOX 8192
#define FDIM  4096
#define H1DIM 64
#define H2DIM 32
#define NW    16

typedef __attribute__((ext_vector_type(8))) _Float16 f16x8;
typedef __attribute__((ext_vector_type(4))) float    f32x4;

typedef __attribute__((address_space(1))) void* gptr_t;
typedef __attribute__((address_space(3))) void* lptr_t;

// async global->LDS, 16B per lane; LDS dest is wave-uniform base + lane*16
__device__ __forceinline__ void g2l16(const void* g, void* l) {
    __builtin_amdgcn_global_load_lds((gptr_t)(uintptr_t)g,
                                     (lptr_t)(uint32_t)(uintptr_t)l,
                                     16, 0, 0);
}

// ---------------- kernel 1: fused prep ----------------
// bx < 512  : gather+transpose W1[words] -> bth[1024][4096] fp16 (16 words x 32 f-tiles)
// bx >= 512 : x fp32 -> fp16 (16384 blocks, 8 floats/thread)
__global__ __launch_bounds__(256) void prep(
    const float* __restrict__ x, _Float16* __restrict__ xh,
    const float* __restrict__ W1, const int* __restrict__ words,
    uint32_t* __restrict__ bth_u32)
{
    __shared__ uint32_t t[64 * 69];   // [c][f/2], pad 69 -> conflict-free
    const int tid = threadIdx.x;

    if (blockIdx.x >= 512) {
        // ---- convert path ----
        const int gid = (blockIdx.x - 512) * 256 + tid;
        const int idx = gid * 8;
        float4 a = *(const float4*)(x + idx);
        float4 b = *(const float4*)(x + idx + 4);
        f16x8 h;
        h[0] = (_Float16)a.x; h[1] = (_Float16)a.y; h[2] = (_Float16)a.z; h[3] = (_Float16)a.w;
        h[4] = (_Float16)b.x; h[5] = (_Float16)b.y; h[6] = (_Float16)b.z; h[7] = (_Float16)b.w;
        *(f16x8*)(xh + idx) = h;
        return;
    }

    // ---- gather path ----
    const int wi = blockIdx.x >> 5;
    const int ft = blockIdx.x & 31;
    const int f0 = ft * 128;
    const int w  = words[wi];
    const int c    = tid & 63;
    const int fgrp = tid >> 6;       // 0..3

    const float* src = W1 + ((size_t)w * FDIM + f0) * H1DIM + c;
#pragma unroll
    for (int p = 0; p < 16; ++p) {
        const int f = fgrp * 2 + p * 8;          // even f in 0..126
        float v0 = src[(size_t)f * H1DIM];        // coalesced (c contiguous)
        float v1 = src[(size_t)(f + 1) * H1DIM];
        union { _Float16 h[2]; uint32_t u; } pk;
        pk.h[0] = (_Float16)v0; pk.h[1] = (_Float16)v1;
        t[c * 69 + (f >> 1)] = pk.u;
    }
    __syncthreads();
#pragma unroll
    for (int p = 0; p < 16; ++p) {
        const int cc = p * 4 + (tid >> 6);
        const int fd = tid & 63;
        bth_u32[(size_t)(wi * 64 + cc) * (FDIM / 2) + ft * 64 + fd] = t[cc * 69 + fd];
    }
}

// ---------------- kernel 2: fused GEMM + tail MLP ----------------
// 128x128 tile, BK=64, 4 waves, 16x16x32 MFMA.
// Block map: mt = bx&63, nt = bx>>6 -> blocks sharing an A M-tile land on one XCD.
// K-loop: cross-kt DOUBLE BUFFER (stage kt+1 before computing kt, ONE barrier/kt)
// so global-load latency hides under ds_read+MFMA of the current tile.
// LDS buffers: per 32KB buf, A[128 rows][64 f16] at +0, B at +16384.
// Bank-conflict-free swizzle: row r, 16B-chunk c stored at byte r*128 + (c^(r&7))*16.
// g2l16 writes linearly (lane*16): lane (lr=lane>>3, slot=lane&7) pre-fetches
// global chunk slot^lr so the swizzled layout lands correctly (both-sides rule).
__global__ __launch_bounds__(256, 2) void gemm_fused(
    const _Float16* __restrict__ xh, const _Float16* __restrict__ bth,
    const float* __restrict__ b1, const int* __restrict__ words,
    const float* __restrict__ W2, const float* __restrict__ b2,
    const float* __restrict__ W3, const float* __restrict__ b3,
    float* __restrict__ sig)   // [NW][NBBOX]
{
    __shared__ __align__(16) char smem[65536];
    float* tile = (float*)smem;   // 64 KB, reused AFTER the final k-loop barrier

    const int mt   = blockIdx.x & 63;   // 64 M-tiles
    const int nt   = blockIdx.x >> 6;   // 8 N-tiles
    const int t    = threadIdx.x;
    const int w    = t >> 6;
    const int lane = t & 63;
    const int m0 = mt * 128, n0 = nt * 128;

    f32x4 acc[4][4] = {};

    // staging addresses (each wave stages rows w*32 .. w*32+31 of A and B)
    const int lr = lane >> 3;            // row within 8-row group
    const int cg = (lane & 7) ^ lr;      // global 16B-chunk this lane fetches
    const _Float16* Ag = xh  + (size_t)(m0 + w * 32 + lr) * FDIM + cg * 8;
    const _Float16* Bg = bth + (size_t)(n0 + w * 32 + lr) * FDIM + cg * 8;
    const int ldst = w * 32 * 128;       // LDS byte base for this wave's rows

    const int wm = w >> 1, wn = w & 1;
    const int ml = lane & 15;
    const int qw = lane >> 4;            // 16B chunk within 32-wide k panel

    // prologue: stage kt=0 into buffer 0
#pragma unroll
    for (int c = 0; c < 4; ++c) {
        g2l16(Ag + (size_t)(c * 8) * FDIM, smem + ldst + c * 1024);
        g2l16(Bg + (size_t)(c * 8) * FDIM, smem + 16384 + ldst + c * 1024);
    }
    __syncthreads();

    int cur = 0;
    for (int kt = 0; kt < 64; ++kt) {
        // stage next tile into the other buffer (flies during compute below)
        if (kt < 63) {
            const int nb = (cur ^ 1) * 32768;
            const size_t ko = (size_t)(kt + 1) * 64;
#pragma unroll
            for (int c = 0; c < 4; ++c) {
                g2l16(Ag + (size_t)(c * 8) * FDIM + ko, smem + nb + ldst + c * 1024);
                g2l16(Bg + (size_t)(c * 8) * FDIM + ko, smem + nb + 16384 + ldst + c * 1024);
            }
        }
        const _Float16* Ab = (const _Float16*)(smem + cur * 32768);
        const _Float16* Bb = (const _Float16*)(smem + cur * 32768 + 16384);
#pragma unroll
        for (int s = 0; s < 2; ++s) {
            f16x8 af[4], bfr[4];
#pragma unroll
            for (int i = 0; i < 4; ++i) {
                const int ra = wm * 64 + i * 16 + ml;
                af[i] = *(const f16x8*)&Ab[ra * 64 + (((s * 4 + qw) ^ (ml & 7)) * 8)];
            }
#pragma unroll
            for (int j = 0; j < 4; ++j) {
                const int rb = wn * 64 + j * 16 + ml;
                bfr[j] = *(const f16x8*)&Bb[rb * 64 + (((s * 4 + qw) ^ (ml & 7)) * 8)];
            }
#pragma unroll
            for (int i = 0; i < 4; ++i)
#pragma unroll
                for (int j = 0; j < 4; ++j)
                    acc[i][j] = __builtin_amdgcn_mfma_f32_16x16x32_f16(af[i], bfr[j], acc[i][j], 0, 0, 0);
        }
        __syncthreads();   // drains stage (vmcnt) + guards buffer swap; final: guards tile reuse
        cur ^= 1;
    }

    // ---- epilogue: bias+relu into wave-private swizzled LDS tile ----
    // C/D layout: col=lane&15, row=quad*4+reg  [m89-verified]
    const int q  = lane >> 4;
    const int wi = nt * 2 + wn;                                   // word slot 0..15
    const int wv = __builtin_amdgcn_readfirstlane(words[wi]);     // force SGPR
    float* tw = tile + w * 4096;                                  // [64 rows][64 k]

#pragma unroll
    for (int j = 0; j < 4; ++j) {
        const int col = j * 16 + ml;                              // k within word, 0..63
        const float bias = b1[wv * H1DIM + col];
        const int c = col >> 2, e = col & 3;
#pragma unroll
        for (int i = 0; i < 4; ++i) {
#pragma unroll
            for (int r = 0; r < 4; ++r) {
                const int row = i * 16 + q * 4 + r;               // local row 0..63
                const int pos = ((c + row) & 7) | (c & 8);        // chunk swizzle
                float v = acc[i][j][r] + bias;
                tw[row * 64 + pos * 4 + e] = v > 0.f ? v : 0.f;
            }
        }
    }
    // wave-private LDS: no barrier needed (compiler inserts lgkmcnt waits)

    // ---- layer 2+3 + sigmoid, one row per lane ----
    const float* W2w = W2 + (size_t)wv * (H1DIM * H2DIM);
    float a2[H2DIM];
#pragma unroll
    for (int j = 0; j < H2DIM; ++j) a2[j] = 0.f;

#pragma unroll
    for (int c2 = 0; c2 < 16; ++c2) {
        const int pos = ((c2 + lane) & 7) | (c2 & 8);
        f32x4 h = *(const f32x4*)&tw[lane * 64 + pos * 4];
#pragma unroll
        for (int kk = 0; kk < 4; ++kk) {
            const float hv = h[kk];
            const int k = c2 * 4 + kk;
#pragma unroll
            for (int j = 0; j < H2DIM; ++j)
                a2[j] = fmaf(hv, W2w[k * H2DIM + j], a2[j]);
        }
    }

    float logit = b3[wv];
#pragma unroll
    for (int j = 0; j < H2DIM; ++j) {
        float h2 = a2[j] + b2[wv * H2DIM + j];
        h2 = h2 > 0.f ? h2 : 0.f;
        logit = fmaf(h2, W3[wv * H2DIM + j], logit);
    }
    sig[(size_t)wi * NBBOX + m0 + wm * 64 + lane] = 1.f / (1.f + expf(-logit));
}

// ---------------- kernel 3: product over words ----------------
__global__ void prod_k(const float* __restrict__ sig, float* __restrict__ out) {
    const int r = blockIdx.x * 256 + threadIdx.x;
    float p = 1.f;
#pragma unroll
    for (int wi = 0; wi < NW; ++wi) p *= sig[(size_t)wi * NBBOX + r];
    out[r] = p;
}

extern "C" void kernel_launch(void* const* d_in, const int* in_sizes, int n_in,
                              void* d_out, int out_size, void* d_ws, size_t ws_size,
                              hipStream_t stream)
{
    const float* x   = (const float*)d_in[1];
    const int* words = (const int*)  d_in[2];
    const float* W1  = (const float*)d_in[3];
    const float* b1  = (const float*)d_in[4];
    const float* W2  = (const float*)d_in[5];
    const float* b2  = (const float*)d_in[6];
    const float* W3  = (const float*)d_in[7];
    const float* b3  = (const float*)d_in[8];
    float* out = (float*)d_out;

    char* ws = (char*)d_ws;
    _Float16* xh  = (_Float16*)(ws);                         // 8192*4096*2  = 64 MiB
    _Float16* bth = (_Float16*)(ws + 67108864);              // 1024*4096*2  = 8 MiB
    float*    sig = (float*)   (ws + 67108864 + 8388608);    // 16*8192*4    = 512 KiB

    prep<<<512 + NBBOX * FDIM / 8 / 256, 256, 0, stream>>>(x, xh, W1, words, (uint32_t*)bth);
    gemm_fused<<<512, 256, 0, stream>>>(xh, bth, b1, words, W2, b2, W3, b3, sig);
    prod_k<<<NBBOX / 256, 256, 0, stream>>>(sig, out);
}